// Round 1
// baseline (139.254 us; speedup 1.0000x reference)
//
#include <hip/hip_runtime.h>
#include <math.h>

#define QD 24
#define KD 24
#define HD 64
#define NN 512
#define DO 128

__device__ __forceinline__ float fast_tanh(float x) {
    // tanh(x) = sign(x) * (1 - e^{-2|x|}) / (1 + e^{-2|x|}); exp via exp2
    float ax = __builtin_fabsf(x);
    float t  = __builtin_amdgcn_exp2f(-2.885390081777927f * ax); // -2*log2(e)*ax
    float r  = (1.0f - t) * __builtin_amdgcn_rcpf(1.0f + t);
    return __builtin_copysignf(r, x);
}

// Kernel A: qk[b,j] = sum_h wk2[j,h] * q[b,h], pre-scaled by 0.125*log2(e).
// q = tanh(fwp @ wq1 + bq1) @ wq2 + bq2. One 64-thread block per b.
__global__ __launch_bounds__(64) void qk_proj(
    const float* __restrict__ fwp,
    const float* __restrict__ wq1, const float* __restrict__ bq1,
    const float* __restrict__ wq2, const float* __restrict__ bq2,
    const float* __restrict__ wk2,
    float* __restrict__ qk_out)
{
    const int b = blockIdx.x;
    const int j = threadIdx.x;
    __shared__ float xf[QD];
    __shared__ float h1[HD];
    __shared__ float qv[HD];
    if (j < QD) xf[j] = fwp[b * QD + j];
    __syncthreads();
    float acc = bq1[j];
#pragma unroll
    for (int k = 0; k < QD; ++k) acc = fmaf(xf[k], wq1[k * HD + j], acc);
    h1[j] = fast_tanh(acc);
    __syncthreads();
    acc = bq2[j];
#pragma unroll
    for (int i = 0; i < HD; ++i) acc = fmaf(h1[i], wq2[i * HD + j], acc);
    qv[j] = acc;
    __syncthreads();
    float s = 0.0f;
#pragma unroll
    for (int h = 0; h < HD; ++h) s = fmaf(wk2[j * HD + h], qv[h], s);
    // fold attention scale (1/8) and log2(e) for exp2-based softmax
    qk_out[b * HD + j] = s * 0.18033688011112042f;
}

// Kernel B: per b: scores (folded K-layer-1 + tanh dotted with qk),
// softmax via shuffles, context = attn @ TO. One 256-thread block per b.
__global__ __launch_bounds__(256) void attn_ctx(
    const float* __restrict__ pwp,   // [B, N, 24]
    const float* __restrict__ to,    // [B, N, 128]
    const float* __restrict__ wk1,   // [24, 64]
    const float* __restrict__ bk1,   // [64]
    const float* __restrict__ qk,    // [B, 64], pre-scaled
    float* __restrict__ out_ctx,     // [B, 128]
    float* __restrict__ out_attn)    // [B, N]
{
    const int b = blockIdx.x;
    const int t = threadIdx.x;

    __shared__ float  s_attn[NN];
    __shared__ float  s_red[8];
    __shared__ float4 s_part[8][32];

    // ---- Phase 1: two score rows per thread (rows t and t+256) ----
    const float* prow0 = pwp + (size_t)b * NN * KD + (size_t)t * KD;
    float x0[KD], x1[KD];
#pragma unroll
    for (int i = 0; i < KD / 4; ++i) {
        float4 v0 = reinterpret_cast<const float4*>(prow0)[i];
        float4 v1 = reinterpret_cast<const float4*>(prow0 + 256 * KD)[i];
        x0[4 * i + 0] = v0.x; x0[4 * i + 1] = v0.y; x0[4 * i + 2] = v0.z; x0[4 * i + 3] = v0.w;
        x1[4 * i + 0] = v1.x; x1[4 * i + 1] = v1.y; x1[4 * i + 2] = v1.z; x1[4 * i + 3] = v1.w;
    }

    const float4* wk1_4 = reinterpret_cast<const float4*>(wk1);
    const float4* bk1_4 = reinterpret_cast<const float4*>(bk1);
    const float4* qk_4  = reinterpret_cast<const float4*>(qk + (size_t)b * HD);

    float sc0 = 0.0f, sc1 = 0.0f;
#pragma unroll 2
    for (int j4 = 0; j4 < HD / 4; ++j4) {
        float4 bb = bk1_4[j4];            // uniform -> scalar load
        float a00 = bb.x, a01 = bb.y, a02 = bb.z, a03 = bb.w;
        float a10 = bb.x, a11 = bb.y, a12 = bb.z, a13 = bb.w;
#pragma unroll
        for (int k = 0; k < KD; ++k) {
            float4 w = wk1_4[k * (HD / 4) + j4];  // uniform -> scalar load
            a00 = fmaf(x0[k], w.x, a00); a01 = fmaf(x0[k], w.y, a01);
            a02 = fmaf(x0[k], w.z, a02); a03 = fmaf(x0[k], w.w, a03);
            a10 = fmaf(x1[k], w.x, a10); a11 = fmaf(x1[k], w.y, a11);
            a12 = fmaf(x1[k], w.z, a12); a13 = fmaf(x1[k], w.w, a13);
        }
        float4 qv = qk_4[j4];             // uniform -> scalar load
        sc0 = fmaf(fast_tanh(a00), qv.x, sc0);
        sc0 = fmaf(fast_tanh(a01), qv.y, sc0);
        sc0 = fmaf(fast_tanh(a02), qv.z, sc0);
        sc0 = fmaf(fast_tanh(a03), qv.w, sc0);
        sc1 = fmaf(fast_tanh(a10), qv.x, sc1);
        sc1 = fmaf(fast_tanh(a11), qv.y, sc1);
        sc1 = fmaf(fast_tanh(a12), qv.z, sc1);
        sc1 = fmaf(fast_tanh(a13), qv.w, sc1);
    }

    // ---- softmax over 512 scores (scores already in exp2 domain) ----
    float m = fmaxf(sc0, sc1);
#pragma unroll
    for (int o = 32; o > 0; o >>= 1) m = fmaxf(m, __shfl_xor(m, o, 64));
    const int wid  = t >> 6;
    const int lane = t & 63;
    if (lane == 0) s_red[wid] = m;
    __syncthreads();
    m = fmaxf(fmaxf(s_red[0], s_red[1]), fmaxf(s_red[2], s_red[3]));

    float e0 = __builtin_amdgcn_exp2f(sc0 - m);
    float e1 = __builtin_amdgcn_exp2f(sc1 - m);
    float ss = e0 + e1;
#pragma unroll
    for (int o = 32; o > 0; o >>= 1) ss += __shfl_xor(ss, o, 64);
    if (lane == 0) s_red[4 + wid] = ss;   // disjoint slots: no extra barrier needed
    __syncthreads();
    ss = (s_red[4] + s_red[5]) + (s_red[6] + s_red[7]);

    const float inv = __builtin_amdgcn_rcpf(ss);
    const float a0 = e0 * inv, a1 = e1 * inv;
    s_attn[t]       = a0;
    s_attn[t + 256] = a1;
    out_attn[(size_t)b * NN + t]       = a0;
    out_attn[(size_t)b * NN + t + 256] = a1;
    __syncthreads();

    // ---- Phase 2: context[b,:] = sum_n attn[n] * TO[b,n,:] ----
    const int g  = t & 31;   // float4 group within the 128-wide row
    const int np = t >> 5;   // n-partition 0..7
    const float4* trow = reinterpret_cast<const float4*>(to + (size_t)b * NN * DO) + g;
    float4 acc = make_float4(0.f, 0.f, 0.f, 0.f);
#pragma unroll 8
    for (int i = 0; i < NN / 8; ++i) {
        const int n = np * (NN / 8) + i;
        const float a = s_attn[n];
        float4 v = trow[(size_t)n * (DO / 4)];
        acc.x = fmaf(a, v.x, acc.x);
        acc.y = fmaf(a, v.y, acc.y);
        acc.z = fmaf(a, v.z, acc.z);
        acc.w = fmaf(a, v.w, acc.w);
    }
    s_part[np][g] = acc;
    __syncthreads();
    if (t < 32) {
        float4 r = s_part[0][t];
#pragma unroll
        for (int p = 1; p < 8; ++p) {
            float4 v = s_part[p][t];
            r.x += v.x; r.y += v.y; r.z += v.z; r.w += v.w;
        }
        reinterpret_cast<float4*>(out_ctx + (size_t)b * DO)[t] = r;
    }
}

extern "C" void kernel_launch(void* const* d_in, const int* in_sizes, int n_in,
                              void* d_out, int out_size, void* d_ws, size_t ws_size,
                              hipStream_t stream) {
    const float* fwp = (const float*)d_in[0];
    const float* pwp = (const float*)d_in[1];
    const float* to  = (const float*)d_in[2];
    const float* wq1 = (const float*)d_in[3];
    const float* bq1 = (const float*)d_in[4];
    const float* wq2 = (const float*)d_in[5];
    const float* bq2 = (const float*)d_in[6];
    const float* wk1 = (const float*)d_in[7];
    const float* bk1 = (const float*)d_in[8];
    const float* wk2 = (const float*)d_in[9];
    // d_in[10] = bk2: per-row constant in the score, cancels in softmax.

    float* out = (float*)d_out;
    float* qk  = (float*)d_ws;                 // B*64 floats = 512 KB scratch
    const int B = in_sizes[0] / QD;            // 2048

    qk_proj<<<B, 64, 0, stream>>>(fwp, wq1, bq1, wq2, bq2, wk2, qk);
    attn_ctx<<<B, 256, 0, stream>>>(pwp, to, wk1, bk1, qk, out,
                                    out + (size_t)B * DO);
}

// Round 2
// 138.629 us; speedup vs baseline: 1.0045x; 1.0045x over previous
//
#include <hip/hip_runtime.h>
#include <math.h>

#define QD 24
#define KD 24
#define HD 64
#define NN 512
#define DO 128
#define CHUNK 128
#define NCHUNK (NN / CHUNK)

__device__ __forceinline__ float fast_tanh(float x) {
    // tanh(x) = sign(x) * (1 - e^{-2|x|}) / (1 + e^{-2|x|}); exp via exp2
    float ax = __builtin_fabsf(x);
    float t  = __builtin_amdgcn_exp2f(-2.885390081777927f * ax); // -2*log2(e)*ax
    float r  = (1.0f - t) * __builtin_amdgcn_rcpf(1.0f + t);
    return __builtin_copysignf(r, x);
}

// One block per b. Waves 0-1 (t<128): score producers. Waves 2-3: context
// consumers streaming TO, pipelined one chunk behind through LDS.
// Softmax shift is the fixed bound Mb = sum|qk| (|tanh|<=1 => s<=Mb), so
// p = exp2(s - Mb) needs no max reduction and no rescaling; softmax is
// exact by shift-invariance.
__global__ __launch_bounds__(256, 8) void fused_attn(
    const float* __restrict__ fwp,   // [B, 24]
    const float* __restrict__ pwp,   // [B, N, 24]
    const float* __restrict__ to,    // [B, N, 128]
    const float* __restrict__ wq1, const float* __restrict__ bq1,
    const float* __restrict__ wq2, const float* __restrict__ bq2,
    const float* __restrict__ wk1, const float* __restrict__ bk1,
    const float* __restrict__ wk2,
    float* __restrict__ out_ctx,     // [B, 128]
    float* __restrict__ out_attn)    // [B, N]
{
    const int b = blockIdx.x;
    const int t = threadIdx.x;

    __shared__ float p_all[NN];      // exp2(s - Mb) for all 512 rows
    __shared__ float xf[QD];
    __shared__ float h1[HD];
    __shared__ float qv[HD];
    __shared__ float qks[HD];        // wk2 @ q, pre-scaled by 0.125*log2e
    __shared__ float4 part[4][32];

    // ---------- fused Q-path + fold of K-layer-2 into qk ----------
    if (t < QD) xf[t] = fwp[(size_t)b * QD + t];
    __syncthreads();
    if (t < HD) {
        float a = bq1[t];
#pragma unroll
        for (int k = 0; k < QD; ++k) a = fmaf(xf[k], wq1[k * HD + t], a);
        h1[t] = fast_tanh(a);
    }
    __syncthreads();
    if (t < HD) {
        float a = bq2[t];
#pragma unroll
        for (int i = 0; i < HD; ++i) a = fmaf(h1[i], wq2[i * HD + t], a);
        qv[t] = a;
    }
    __syncthreads();
    if (t < HD) {
        float s = 0.0f;
#pragma unroll
        for (int h = 0; h < HD; ++h) s = fmaf(wk2[t * HD + h], qv[h], s);
        qks[t] = s * 0.18033688011112042f;  // (1/8) * log2(e)
    }
    __syncthreads();

    // fixed softmax shift (safe upper bound on every score)
    float Mb = 0.0f;
#pragma unroll
    for (int h = 0; h < HD; ++h) Mb += __builtin_fabsf(qks[h]);

    const bool is_prod = (t < 128);
    const int ct = t - 128;          // consumer id (valid when !is_prod)
    const int g  = ct & 31;          // float4 column group 0..31
    const int r  = (ct >> 5) & 3;    // row partition 0..3

    const float4* trow = reinterpret_cast<const float4*>(to + (size_t)b * NN * DO) + g;
    float4 acc = make_float4(0.f, 0.f, 0.f, 0.f);

    auto consume = [&](int cc) {
        const int n0 = cc * CHUNK + r * 32;
#pragma unroll 8
        for (int i = 0; i < 32; ++i) {
            const int n = n0 + i;
            const float p = p_all[n];
            float4 v = trow[(size_t)n * (DO / 4)];
            acc.x = fmaf(p, v.x, acc.x);
            acc.y = fmaf(p, v.y, acc.y);
            acc.z = fmaf(p, v.z, acc.z);
            acc.w = fmaf(p, v.w, acc.w);
        }
    };

    const float4* wk1_4 = reinterpret_cast<const float4*>(wk1);
    const float4* bk1_4 = reinterpret_cast<const float4*>(bk1);
    const float4* qks_4 = reinterpret_cast<const float4*>(qks);

    // ---------- pipelined chunk loop ----------
    for (int c = 0; c < NCHUNK; ++c) {
        if (is_prod) {
            const int n = c * CHUNK + t;
            const float* prow = pwp + ((size_t)b * NN + n) * KD;
            float x[KD];
#pragma unroll
            for (int i = 0; i < KD / 4; ++i) {
                float4 v = reinterpret_cast<const float4*>(prow)[i];
                x[4 * i + 0] = v.x; x[4 * i + 1] = v.y;
                x[4 * i + 2] = v.z; x[4 * i + 3] = v.w;
            }
            float sc = 0.0f;
#pragma unroll 2
            for (int j4 = 0; j4 < HD / 4; ++j4) {
                float4 bb = bk1_4[j4];
                float a0 = bb.x, a1 = bb.y, a2 = bb.z, a3 = bb.w;
#pragma unroll
                for (int k = 0; k < KD; ++k) {
                    float4 w = wk1_4[k * (HD / 4) + j4];
                    a0 = fmaf(x[k], w.x, a0); a1 = fmaf(x[k], w.y, a1);
                    a2 = fmaf(x[k], w.z, a2); a3 = fmaf(x[k], w.w, a3);
                }
                float4 qq = qks_4[j4];   // LDS broadcast read
                sc = fmaf(fast_tanh(a0), qq.x, sc);
                sc = fmaf(fast_tanh(a1), qq.y, sc);
                sc = fmaf(fast_tanh(a2), qq.z, sc);
                sc = fmaf(fast_tanh(a3), qq.w, sc);
            }
            p_all[n] = __builtin_amdgcn_exp2f(sc - Mb);
        } else if (c > 0) {
            consume(c - 1);
        }
        __syncthreads();
    }

    // ---------- epilogue ----------
    float invL = 0.0f;
    if (!is_prod) {
        consume(NCHUNK - 1);         // last chunk (p_all fully written)
        part[r][g] = acc;
    } else if (t < 64) {
        // wave 0: denominator + attn output, overlapped with consumers' tail
        float l = 0.0f;
#pragma unroll
        for (int i = 0; i < NN / 64; ++i) l += p_all[t + 64 * i];
#pragma unroll
        for (int o = 32; o > 0; o >>= 1) l += __shfl_xor(l, o, 64);
        invL = __builtin_amdgcn_rcpf(l);
        float* oa = out_attn + (size_t)b * NN;
#pragma unroll
        for (int i = 0; i < NN / 64; ++i) oa[t + 64 * i] = p_all[t + 64 * i] * invL;
    }
    __syncthreads();

    if (t < 32) {                    // wave 0 still holds invL
        float4 r0 = part[0][t], r1 = part[1][t], r2 = part[2][t], r3 = part[3][t];
        float4 o;
        o.x = ((r0.x + r1.x) + (r2.x + r3.x)) * invL;
        o.y = ((r0.y + r1.y) + (r2.y + r3.y)) * invL;
        o.z = ((r0.z + r1.z) + (r2.z + r3.z)) * invL;
        o.w = ((r0.w + r1.w) + (r2.w + r3.w)) * invL;
        reinterpret_cast<float4*>(out_ctx + (size_t)b * DO)[t] = o;
    }
}

extern "C" void kernel_launch(void* const* d_in, const int* in_sizes, int n_in,
                              void* d_out, int out_size, void* d_ws, size_t ws_size,
                              hipStream_t stream) {
    const float* fwp = (const float*)d_in[0];
    const float* pwp = (const float*)d_in[1];
    const float* to  = (const float*)d_in[2];
    const float* wq1 = (const float*)d_in[3];
    const float* bq1 = (const float*)d_in[4];
    const float* wq2 = (const float*)d_in[5];
    const float* bq2 = (const float*)d_in[6];
    const float* wk1 = (const float*)d_in[7];
    const float* bk1 = (const float*)d_in[8];
    const float* wk2 = (const float*)d_in[9];
    // d_in[10] = bk2: adds a per-row constant to every score -> cancels in softmax.

    float* out = (float*)d_out;
    const int B = in_sizes[0] / QD;  // 2048

    fused_attn<<<B, 256, 0, stream>>>(fwp, pwp, to, wq1, bq1, wq2, bq2,
                                      wk1, bk1, wk2,
                                      out, out + (size_t)B * DO);
}